// Round 1
// baseline (211.453 us; speedup 1.0000x reference)
//
#include <hip/hip_runtime.h>
#include <hip/hip_bf16.h>
#include <stdint.h>

typedef __bf16 bf16x8 __attribute__((ext_vector_type(8)));
typedef float  f32x4  __attribute__((ext_vector_type(4)));
typedef unsigned short u16_t;
typedef u16_t u16x4 __attribute__((ext_vector_type(4)));

#define MFMA(a, b, c) __builtin_amdgcn_mfma_f32_16x16x32_bf16((a), (b), (c), 0, 0, 0)

// async global->LDS, 16B per lane; LDS dest is wave-uniform base + lane*16
__device__ __forceinline__ void cp16(const void* g, void* l) {
  __builtin_amdgcn_global_load_lds(
      (const __attribute__((address_space(1))) unsigned int*)g,
      (__attribute__((address_space(3))) unsigned int*)l, 16, 0, 0);
}

__device__ __forceinline__ u16_t f2b(float f) {  // fp32 -> bf16 (RNE)
  union { float f; unsigned int u; } v; v.f = f;
  unsigned int u = v.u;
  return (u16_t)((u + 0x7fffu + ((u >> 16) & 1u)) >> 16);
}

// ---------------- kernel 1: x fp32 -> bf16 ----------------
__global__ __launch_bounds__(256) void k_cvt_x(const float* __restrict__ in,
                                               u16_t* __restrict__ out, int n4) {
  int i = blockIdx.x * 256 + threadIdx.x;
  if (i >= n4) return;
  float4 f = ((const float4*)in)[i];
  u16x4 o; o.x = f2b(f.x); o.y = f2b(f.y); o.z = f2b(f.z); o.w = f2b(f.w);
  *(u16x4*)&out[(size_t)i * 4] = o;
}

// ------- kernel 2: W[k][n] fp32 -> Wt[mat*1024+n][k] bf16 (transpose) -------
__global__ __launch_bounds__(256) void k_cvt_w(const float* __restrict__ W0,
                                               const float* __restrict__ W1,
                                               const float* __restrict__ W2,
                                               u16_t* __restrict__ Wt) {
  __shared__ u16_t T[64][65];
  const float* W = blockIdx.z == 0 ? W0 : (blockIdx.z == 1 ? W1 : W2);
  int k0 = blockIdx.y * 64, n0 = blockIdx.x * 64;
  int t = threadIdx.x;
#pragma unroll
  for (int i = 0; i < 16; i++) {
    int e = i * 256 + t, r = e >> 6, c = e & 63;
    T[r][c] = f2b(W[(size_t)(k0 + r) * 1024 + n0 + c]);
  }
  __syncthreads();
  size_t base = ((size_t)blockIdx.z * 1024 + n0) * 1024 + k0;
#pragma unroll
  for (int i = 0; i < 16; i++) {
    int e = i * 256 + t, r = e >> 6, c = e & 63;
    Wt[base + (size_t)r * 1024 + c] = T[c][r];
  }
}

// ---------------- kernel 3: fused QKV GEMM (m97 structure) ----------------
// C[4096,3072] = A[4096,1024] @ Bt[3072,1024]^T, +bias, scatter to Q/K/V [bh][s][dk] bf16
__global__ __launch_bounds__(256) void k_gemm_qkv(
    const u16_t* __restrict__ A, const u16_t* __restrict__ Bt,
    const float* __restrict__ bq, const float* __restrict__ bk,
    const float* __restrict__ bv,
    u16_t* __restrict__ Qo, u16_t* __restrict__ Ko, u16_t* __restrict__ Vo) {
  __shared__ u16_t As[128 * 32];
  __shared__ u16_t Bs[128 * 32];
  const int tid = threadIdx.x, lane = tid & 63, wv = tid >> 6;
  const int quad = lane >> 4, col = lane & 15;
  const int wm = wv >> 1, wn = wv & 1;
  const int tn = blockIdx.x * 128, tm = blockIdx.y * 128;
  f32x4 acc[4][4] = {};

  const int c0 = wv * 2;
  const int srow = lane >> 2;   // row within 16-row chunk
  const int spc = lane & 3;     // physical 16B k-chunk

  for (int kk = 0; kk < 1024; kk += 32) {
#pragma unroll
    for (int i = 0; i < 2; i++) {
      int c = c0 + i;
      int m = c * 16 + srow;
      int lch = spc ^ ((m >> 1) & 3);  // XOR swizzle (bank-conflict-free frag reads)
      cp16(A + (size_t)(tm + m) * 1024 + kk + lch * 8, As + c * 512 + lane * 8);
      cp16(Bt + (size_t)(tn + m) * 1024 + kk + lch * 8, Bs + c * 512 + lane * 8);
    }
    __syncthreads();
    bf16x8 af[4], bfv[4];
#pragma unroll
    for (int mt = 0; mt < 4; mt++) {
      int row = wm * 64 + mt * 16 + col;
      af[mt] = *(const bf16x8*)&As[row * 32 + (quad ^ ((row >> 1) & 3)) * 8];
    }
#pragma unroll
    for (int nt = 0; nt < 4; nt++) {
      int row = wn * 64 + nt * 16 + col;
      bfv[nt] = *(const bf16x8*)&Bs[row * 32 + (quad ^ ((row >> 1) & 3)) * 8];
    }
#pragma unroll
    for (int mt = 0; mt < 4; mt++)
#pragma unroll
      for (int nt = 0; nt < 4; nt++)
        acc[mt][nt] = MFMA(af[mt], bfv[nt], acc[mt][nt]);
    __syncthreads();
  }

  const int mat = tn >> 10;  // uniform per block (128 | 1024)
  const float* bias = mat == 0 ? bq : (mat == 1 ? bk : bv);
  u16_t* O = mat == 0 ? Qo : (mat == 1 ? Ko : Vo);
#pragma unroll
  for (int nt = 0; nt < 4; nt++) {
    int gn = tn + wn * 64 + nt * 16 + col;
    int d = gn & 1023;
    int h = d >> 6, dk = d & 63;
    float bb = bias[d];
#pragma unroll
    for (int mt = 0; mt < 4; mt++) {
#pragma unroll
      for (int r = 0; r < 4; r++) {
        int gm = tm + wm * 64 + mt * 16 + quad * 4 + r;
        int b = gm >> 11, s = gm & 2047;
        O[((size_t)((b * 16 + h) * 2048 + s)) * 64 + dk] = f2b(acc[mt][nt][r] + bb);
      }
    }
  }
}

// ---------------- kernel 4: V[bh][s][dk] -> Vt[bh][dk][s] ----------------
__global__ __launch_bounds__(256) void k_trans_v(const u16_t* __restrict__ V,
                                                 u16_t* __restrict__ Vt) {
  __shared__ u16_t T[64][65];
  int bh = blockIdx.y, s0 = blockIdx.x * 64;
  int t = threadIdx.x;
#pragma unroll
  for (int i = 0; i < 16; i++) {
    int e = i * 256 + t, r = e >> 6, c = e & 63;
    T[r][c] = V[((size_t)bh * 2048 + s0 + r) * 64 + c];
  }
  __syncthreads();
#pragma unroll
  for (int i = 0; i < 16; i++) {
    int e = i * 256 + t, r = e >> 6, c = e & 63;
    Vt[((size_t)bh * 64 + r) * 2048 + s0 + c] = T[c][r];
  }
}

// ---------------- kernel 5: fused attention ----------------
// per block: one (b,h), 128-query tile; loop 64-key tiles; exp (no max-sub per
// reference), accumulate num=P@V (MFMA) and den=rowsum(P); out = num/(den+1e-8)
__global__ __launch_bounds__(256) void k_attn(const u16_t* __restrict__ Q,
                                              const u16_t* __restrict__ K,
                                              const u16_t* __restrict__ Vt,
                                              float* __restrict__ out) {
  __shared__ u16_t Qs[128 * 64];
  __shared__ u16_t Ks[64 * 64];
  __shared__ u16_t Vts[64 * 64];
  __shared__ u16_t Ps[128 * 64];
  __shared__ float dens[128];
  const int tid = threadIdx.x, lane = tid & 63, wv = tid >> 6;
  const int quad = lane >> 4, col = lane & 15;
  const int wm = wv >> 1, wn = wv & 1;
  const int qt = blockIdx.x, bh = blockIdx.y;
  const int b = bh >> 4, h = bh & 15;
  const float SC = 0.18033688011112042f;  // log2(e)/sqrt(64)

  const u16_t* Qg = Q + ((size_t)bh * 2048 + qt * 128) * 64;
  const int r8 = lane >> 3, c8p = lane & 7;
#pragma unroll
  for (int i = 0; i < 4; i++) {  // Qs: 16KB, XOR-8 swizzled rows
    int c = wv * 4 + i;
    int row = c * 8 + r8;
    int lch = c8p ^ (row & 7);
    cp16(Qg + (size_t)row * 64 + lch * 8, Qs + c * 512 + lane * 8);
  }

  f32x4 ao[4][2] = {};
  float den = 0.f;

  for (int kt = 0; kt < 32; ++kt) {
    const u16_t* Kg = K + ((size_t)bh * 2048 + kt * 64) * 64;
#pragma unroll
    for (int i = 0; i < 2; i++) {
      int c = wv * 2 + i;
      int row = c * 8 + r8;
      int lch = c8p ^ (row & 7);
      cp16(Kg + (size_t)row * 64 + lch * 8, Ks + c * 512 + lane * 8);
      cp16(Vt + ((size_t)bh * 64 + row) * 2048 + kt * 64 + lch * 8,
           Vts + c * 512 + lane * 8);
    }
    __syncthreads();

    // scores: S[128q][64k] = Q @ K^T   (M=128,N=64,K=64)
    f32x4 sc[4][2] = {};
#pragma unroll
    for (int ks = 0; ks < 2; ks++) {
      bf16x8 af[4], bfv[2];
#pragma unroll
      for (int mt = 0; mt < 4; mt++) {
        int row = wm * 64 + mt * 16 + col;
        af[mt] = *(const bf16x8*)&Qs[row * 64 + ((ks * 4 + quad) ^ (row & 7)) * 8];
      }
#pragma unroll
      for (int nt = 0; nt < 2; nt++) {
        int row = wn * 32 + nt * 16 + col;
        bfv[nt] = *(const bf16x8*)&Ks[row * 64 + ((ks * 4 + quad) ^ (row & 7)) * 8];
      }
#pragma unroll
      for (int mt = 0; mt < 4; mt++)
#pragma unroll
        for (int nt = 0; nt < 2; nt++)
          sc[mt][nt] = MFMA(af[mt], bfv[nt], sc[mt][nt]);
    }

    // P = exp(S/8) -> bf16 -> LDS (C-layout scatter, swizzled)
#pragma unroll
    for (int mt = 0; mt < 4; mt++) {
#pragma unroll
      for (int nt = 0; nt < 2; nt++) {
        int cl = wn * 32 + nt * 16 + col;
#pragma unroll
        for (int r = 0; r < 4; r++) {
          int row = wm * 64 + mt * 16 + quad * 4 + r;
          float e = exp2f(sc[mt][nt][r] * SC);
          Ps[row * 64 + (((cl >> 3) ^ (row & 7)) * 8) + (cl & 7)] = f2b(e);
        }
      }
    }
    __syncthreads();

    // den: row-sums of P (threads 0..127 own one row each)
    if (tid < 128) {
#pragma unroll
      for (int c8 = 0; c8 < 8; c8++) {
        bf16x8 p = *(const bf16x8*)&Ps[tid * 64 + ((c8 ^ (tid & 7)) * 8)];
#pragma unroll
        for (int j = 0; j < 8; j++) den += (float)p[j];
      }
    }

    // O += P @ V   (M=128,N=64,K=64) ; B-operand from V^T tile
#pragma unroll
    for (int ks = 0; ks < 2; ks++) {
      bf16x8 af[4], bfv[2];
#pragma unroll
      for (int mt = 0; mt < 4; mt++) {
        int row = wm * 64 + mt * 16 + col;
        af[mt] = *(const bf16x8*)&Ps[row * 64 + ((ks * 4 + quad) ^ (row & 7)) * 8];
      }
#pragma unroll
      for (int nt = 0; nt < 2; nt++) {
        int row = wn * 32 + nt * 16 + col;
        bfv[nt] = *(const bf16x8*)&Vts[row * 64 + ((ks * 4 + quad) ^ (row & 7)) * 8];
      }
#pragma unroll
      for (int mt = 0; mt < 4; mt++)
#pragma unroll
        for (int nt = 0; nt < 2; nt++)
          ao[mt][nt] = MFMA(af[mt], bfv[nt], ao[mt][nt]);
    }
    __syncthreads();  // protect Ks/Vts/Ps before next stage
  }

  if (tid < 128) dens[tid] = den;
  __syncthreads();

#pragma unroll
  for (int nt = 0; nt < 2; nt++) {
    int dcol = wn * 32 + nt * 16 + col;
#pragma unroll
    for (int mt = 0; mt < 4; mt++) {
#pragma unroll
      for (int r = 0; r < 4; r++) {
        int row = wm * 64 + mt * 16 + quad * 4 + r;
        float vv = ao[mt][nt][r] / (dens[row] + 1e-8f);
        int s = qt * 128 + row;
        out[((size_t)b * 2048 + s) * 1024 + h * 64 + dcol] = vv;
      }
    }
  }
}

// ---------------- launcher ----------------
extern "C" void kernel_launch(void* const* d_in, const int* in_sizes, int n_in,
                              void* d_out, int out_size, void* d_ws, size_t ws_size,
                              hipStream_t stream) {
  const float* x  = (const float*)d_in[0];
  const float* Wq = (const float*)d_in[1];
  const float* bq = (const float*)d_in[2];
  const float* Wk = (const float*)d_in[3];
  const float* bk = (const float*)d_in[4];
  const float* Wv = (const float*)d_in[5];
  const float* bv = (const float*)d_in[6];
  float* out = (float*)d_out;

  char* ws = (char*)d_ws;
  u16_t* xb  = (u16_t*)(ws);                 // 8 MB   x bf16 [4096][1024]
  u16_t* Wt  = (u16_t*)(ws + 8388608);       // 6 MB   Wt bf16 [3072][1024]
  u16_t* Qb  = (u16_t*)(ws + 14680064);      // 8 MB   Q bf16 [32][2048][64]
  u16_t* Kb  = (u16_t*)(ws + 23068672);      // 8 MB   K bf16
  u16_t* Vb  = (u16_t*)(ws + 31457280);      // 8 MB   V bf16
  u16_t* Vtb = (u16_t*)(ws + 39845888);      // 8 MB   V^T bf16 [32][64][2048]

  hipLaunchKernelGGL(k_cvt_x, dim3(4096), dim3(256), 0, stream, x, xb, 1048576);
  hipLaunchKernelGGL(k_cvt_w, dim3(16, 16, 3), dim3(256), 0, stream, Wq, Wk, Wv, Wt);
  hipLaunchKernelGGL(k_gemm_qkv, dim3(24, 32), dim3(256), 0, stream,
                     xb, Wt, bq, bk, bv, Qb, Kb, Vb);
  hipLaunchKernelGGL(k_trans_v, dim3(32, 32), dim3(256), 0, stream, Vb, Vtb);
  hipLaunchKernelGGL(k_attn, dim3(16, 32), dim3(256), 0, stream, Qb, Kb, Vtb, out);
}

// Round 2
// 192.238 us; speedup vs baseline: 1.1000x; 1.1000x over previous
//
#include <hip/hip_runtime.h>
#include <hip/hip_bf16.h>
#include <stdint.h>

typedef __bf16 bf16x8 __attribute__((ext_vector_type(8)));
typedef __bf16 bf16x4 __attribute__((ext_vector_type(4)));
typedef float  f32x4  __attribute__((ext_vector_type(4)));
typedef unsigned short u16_t;

#define MFMA(a, b, c) __builtin_amdgcn_mfma_f32_16x16x32_bf16((a), (b), (c), 0, 0, 0)

// async global->LDS, 16B per lane; LDS dest is wave-uniform base + lane*16
__device__ __forceinline__ void cp16(const void* g, void* l) {
  __builtin_amdgcn_global_load_lds(
      (const __attribute__((address_space(1))) unsigned int*)g,
      (__attribute__((address_space(3))) unsigned int*)l, 16, 0, 0);
}

// ---------------- kernel 1: x fp32 -> bf16 ----------------
__global__ __launch_bounds__(256) void k_cvt_x(const float* __restrict__ in,
                                               u16_t* __restrict__ out, int n4) {
  int i = blockIdx.x * 256 + threadIdx.x;
  if (i >= n4) return;
  float4 f = ((const float4*)in)[i];
  bf16x4 o = {(__bf16)f.x, (__bf16)f.y, (__bf16)f.z, (__bf16)f.w};
  *(bf16x4*)&out[(size_t)i * 4] = o;
}

// ------- kernel 2: W[k][n] fp32 -> Wt[mat*1024+n][k] bf16 (transpose) -------
__global__ __launch_bounds__(256) void k_cvt_w(const float* __restrict__ W0,
                                               const float* __restrict__ W1,
                                               const float* __restrict__ W2,
                                               u16_t* __restrict__ Wt) {
  __shared__ u16_t T[64][65];
  const float* W = blockIdx.z == 0 ? W0 : (blockIdx.z == 1 ? W1 : W2);
  int k0 = blockIdx.y * 64, n0 = blockIdx.x * 64;
  int t = threadIdx.x;
#pragma unroll
  for (int i = 0; i < 16; i++) {
    int e = i * 256 + t, r = e >> 6, c = e & 63;
    __bf16 hv = (__bf16)W[(size_t)(k0 + r) * 1024 + n0 + c];
    T[r][c] = *(u16_t*)&hv;
  }
  __syncthreads();
  size_t base = ((size_t)blockIdx.z * 1024 + n0) * 1024 + k0;
#pragma unroll
  for (int i = 0; i < 16; i++) {
    int e = i * 256 + t, r = e >> 6, c = e & 63;
    Wt[base + (size_t)r * 1024 + c] = T[c][r];
  }
}

// ---------------- kernel 3: fused QKV GEMM (m97 structure) ----------------
// C[4096,3072] = A[4096,1024] @ Bt[3072,1024]^T, +bias, scatter to Q/K/V [bh][s][dk] bf16
__global__ __launch_bounds__(256) void k_gemm_qkv(
    const u16_t* __restrict__ A, const u16_t* __restrict__ Bt,
    const float* __restrict__ bq, const float* __restrict__ bk,
    const float* __restrict__ bv,
    u16_t* __restrict__ Qo, u16_t* __restrict__ Ko, u16_t* __restrict__ Vo) {
  __shared__ u16_t As[128 * 32];
  __shared__ u16_t Bs[128 * 32];
  const int tid = threadIdx.x, lane = tid & 63, wv = tid >> 6;
  const int quad = lane >> 4, col = lane & 15;
  const int wm = wv >> 1, wn = wv & 1;
  const int tn = blockIdx.x * 128, tm = blockIdx.y * 128;
  f32x4 acc[4][4] = {};

  const int c0 = wv * 2;
  const int srow = lane >> 2;   // row within 16-row chunk
  const int spc = lane & 3;     // physical 16B k-chunk

  for (int kk = 0; kk < 1024; kk += 32) {
#pragma unroll
    for (int i = 0; i < 2; i++) {
      int c = c0 + i;
      int m = c * 16 + srow;
      int lch = spc ^ ((m >> 1) & 3);  // XOR swizzle (bank-conflict-free frag reads)
      cp16(A + (size_t)(tm + m) * 1024 + kk + lch * 8, As + c * 512 + lane * 8);
      cp16(Bt + (size_t)(tn + m) * 1024 + kk + lch * 8, Bs + c * 512 + lane * 8);
    }
    __syncthreads();
    bf16x8 af[4], bfv[4];
#pragma unroll
    for (int mt = 0; mt < 4; mt++) {
      int row = wm * 64 + mt * 16 + col;
      af[mt] = *(const bf16x8*)&As[row * 32 + (quad ^ ((row >> 1) & 3)) * 8];
    }
#pragma unroll
    for (int nt = 0; nt < 4; nt++) {
      int row = wn * 64 + nt * 16 + col;
      bfv[nt] = *(const bf16x8*)&Bs[row * 32 + (quad ^ ((row >> 1) & 3)) * 8];
    }
#pragma unroll
    for (int mt = 0; mt < 4; mt++)
#pragma unroll
      for (int nt = 0; nt < 4; nt++)
        acc[mt][nt] = MFMA(af[mt], bfv[nt], acc[mt][nt]);
    __syncthreads();
  }

  const int mat = tn >> 10;  // uniform per block (128 | 1024)
  const float* bias = mat == 0 ? bq : (mat == 1 ? bk : bv);
  u16_t* O = mat == 0 ? Qo : (mat == 1 ? Ko : Vo);
#pragma unroll
  for (int nt = 0; nt < 4; nt++) {
    int gn = tn + wn * 64 + nt * 16 + col;
    int d = gn & 1023;
    int h = d >> 6, dk = d & 63;
    float bb = bias[d];
#pragma unroll
    for (int mt = 0; mt < 4; mt++) {
#pragma unroll
      for (int r = 0; r < 4; r++) {
        int gm = tm + wm * 64 + mt * 16 + quad * 4 + r;
        int b = gm >> 11, s = gm & 2047;
        __bf16 hv = (__bf16)(acc[mt][nt][r] + bb);
        O[((size_t)((b * 16 + h) * 2048 + s)) * 64 + dk] = *(u16_t*)&hv;
      }
    }
  }
}

// ---------------- kernel 4: V[bh][s][dk] -> Vt[bh][dk][s] ----------------
__global__ __launch_bounds__(256) void k_trans_v(const u16_t* __restrict__ V,
                                                 u16_t* __restrict__ Vt) {
  __shared__ u16_t T[64][65];
  int bh = blockIdx.y, s0 = blockIdx.x * 64;
  int t = threadIdx.x;
#pragma unroll
  for (int i = 0; i < 16; i++) {
    int e = i * 256 + t, r = e >> 6, c = e & 63;
    T[r][c] = V[((size_t)bh * 2048 + s0 + r) * 64 + c];
  }
  __syncthreads();
#pragma unroll
  for (int i = 0; i < 16; i++) {
    int e = i * 256 + t, r = e >> 6, c = e & 63;
    Vt[((size_t)bh * 64 + r) * 2048 + s0 + c] = T[c][r];
  }
}

// ---------------- kernel 5: fused attention (v2) ----------------
// 64-query tile per block (grid 32x32 = 1024 blocks -> 4 blocks/CU).
// Q fragments in registers; its LDS region reused for P. K/V double-buffered.
// den computed via MFMA(P, ones) -> per-row sums land in C-layout registers.
__global__ __launch_bounds__(256, 4) void k_attn(const u16_t* __restrict__ Q,
                                                 const u16_t* __restrict__ K,
                                                 const u16_t* __restrict__ Vt,
                                                 float* __restrict__ out) {
  __shared__ u16_t Ps[64 * 64];        // 8K: Q staging, then P tile
  __shared__ u16_t Ks[2][64 * 64];     // 16K double-buffered
  __shared__ u16_t Vts[2][64 * 64];    // 16K double-buffered
  const int tid = threadIdx.x, lane = tid & 63, wv = tid >> 6;
  const int quad = lane >> 4, col = lane & 15;
  const int wm = wv >> 1, wn = wv & 1;
  const int qt = blockIdx.x, bh = blockIdx.y;
  const int b = bh >> 4, h = bh & 15;
  const float SC = 0.18033688011112042f;  // log2(e)/sqrt(64)

  const int r8 = lane >> 3, c8p = lane & 7;
  const u16_t* Qg = Q + ((size_t)bh * 2048 + qt * 64) * 64;
  const u16_t* Kg = K + (size_t)bh * 2048 * 64;
  const u16_t* Vg = Vt + (size_t)bh * 64 * 2048;

  // stage Q (into Ps region) + first K/V tiles, all XOR-8 swizzled
#pragma unroll
  for (int i = 0; i < 2; i++) {
    int c = wv * 2 + i;
    int row = c * 8 + r8;
    int lch = c8p ^ (row & 7);
    cp16(Qg + (size_t)row * 64 + lch * 8, Ps + c * 512 + lane * 8);
    cp16(Kg + (size_t)row * 64 + lch * 8, Ks[0] + c * 512 + lane * 8);
    cp16(Vg + (size_t)row * 2048 + lch * 8, Vts[0] + c * 512 + lane * 8);
  }
  __syncthreads();

  // Q fragments -> registers (wave-private rows wm*32..+31)
  bf16x8 qf[2][2];
#pragma unroll
  for (int mt = 0; mt < 2; mt++)
#pragma unroll
    for (int ks = 0; ks < 2; ks++) {
      int row = wm * 32 + mt * 16 + col;
      qf[mt][ks] = *(const bf16x8*)&Ps[row * 64 + (((ks * 4 + quad) ^ (row & 7)) * 8)];
    }

  bf16x8 ones;
#pragma unroll
  for (int j = 0; j < 8; j++) ones[j] = (__bf16)1.0f;

  f32x4 ao[2][2] = {};
  f32x4 dn[2] = {};

  for (int kt = 0; kt < 32; ++kt) {
    const int cur = kt & 1;
    __syncthreads();  // kt=0: Q-frag reads done (Ps free); kt>0: prev PV reads done

    // prefetch next K/V tiles into the other buffer
    if (kt + 1 < 32) {
#pragma unroll
      for (int i = 0; i < 2; i++) {
        int c = wv * 2 + i;
        int row = c * 8 + r8;
        int lch = c8p ^ (row & 7);
        cp16(Kg + (size_t)(kt + 1) * 64 * 64 + (size_t)row * 64 + lch * 8,
             Ks[cur ^ 1] + c * 512 + lane * 8);
        cp16(Vg + (size_t)row * 2048 + (kt + 1) * 64 + lch * 8,
             Vts[cur ^ 1] + c * 512 + lane * 8);
      }
    }

    // scores: S[64q][64k] = Q @ K^T
    f32x4 sc[2][2] = {};
#pragma unroll
    for (int ks = 0; ks < 2; ks++) {
      bf16x8 kf[2];
#pragma unroll
      for (int nt = 0; nt < 2; nt++) {
        int row = wn * 32 + nt * 16 + col;
        kf[nt] = *(const bf16x8*)&Ks[cur][row * 64 + (((ks * 4 + quad) ^ (row & 7)) * 8)];
      }
#pragma unroll
      for (int mt = 0; mt < 2; mt++)
#pragma unroll
        for (int nt = 0; nt < 2; nt++)
          sc[mt][nt] = MFMA(qf[mt][ks], kf[nt], sc[mt][nt]);
    }

    // P = exp(S/8) -> bf16 -> LDS (C-layout scatter, swizzled)
#pragma unroll
    for (int mt = 0; mt < 2; mt++) {
#pragma unroll
      for (int nt = 0; nt < 2; nt++) {
        int cl = wn * 32 + nt * 16 + col;
#pragma unroll
        for (int r = 0; r < 4; r++) {
          int row = wm * 32 + mt * 16 + quad * 4 + r;
          __bf16 pv = (__bf16)exp2f(sc[mt][nt][r] * SC);
          Ps[row * 64 + (((cl >> 3) ^ (row & 7)) * 8) + (cl & 7)] = *(u16_t*)&pv;
        }
      }
    }
    __syncthreads();  // Ps visible to partner wave

    // O += P @ V ; den += P @ 1
#pragma unroll
    for (int ks = 0; ks < 2; ks++) {
      bf16x8 pf[2], vf[2];
#pragma unroll
      for (int mt = 0; mt < 2; mt++) {
        int row = wm * 32 + mt * 16 + col;
        pf[mt] = *(const bf16x8*)&Ps[row * 64 + (((ks * 4 + quad) ^ (row & 7)) * 8)];
      }
#pragma unroll
      for (int nt = 0; nt < 2; nt++) {
        int row = wn * 32 + nt * 16 + col;
        vf[nt] = *(const bf16x8*)&Vts[cur][row * 64 + (((ks * 4 + quad) ^ (row & 7)) * 8)];
      }
#pragma unroll
      for (int mt = 0; mt < 2; mt++) {
#pragma unroll
        for (int nt = 0; nt < 2; nt++)
          ao[mt][nt] = MFMA(pf[mt], vf[nt], ao[mt][nt]);
        dn[mt] = MFMA(pf[mt], ones, dn[mt]);
      }
    }
  }

  // epilogue: normalize, write fp32 out [b][s][h*64+d]
#pragma unroll
  for (int mt = 0; mt < 2; mt++) {
#pragma unroll
    for (int nt = 0; nt < 2; nt++) {
      int dcol = wn * 32 + nt * 16 + col;
#pragma unroll
      for (int r = 0; r < 4; r++) {
        int row = wm * 32 + mt * 16 + quad * 4 + r;
        float vv = ao[mt][nt][r] / (dn[mt][r] + 1e-8f);
        int s = qt * 64 + row;
        out[((size_t)b * 2048 + s) * 1024 + h * 64 + dcol] = vv;
      }
    }
  }
}

// ---------------- launcher ----------------
extern "C" void kernel_launch(void* const* d_in, const int* in_sizes, int n_in,
                              void* d_out, int out_size, void* d_ws, size_t ws_size,
                              hipStream_t stream) {
  const float* x  = (const float*)d_in[0];
  const float* Wq = (const float*)d_in[1];
  const float* bq = (const float*)d_in[2];
  const float* Wk = (const float*)d_in[3];
  const float* bk = (const float*)d_in[4];
  const float* Wv = (const float*)d_in[5];
  const float* bv = (const float*)d_in[6];
  float* out = (float*)d_out;

  char* ws = (char*)d_ws;
  u16_t* xb  = (u16_t*)(ws);                 // 8 MB   x bf16 [4096][1024]
  u16_t* Wt  = (u16_t*)(ws + 8388608);       // 6 MB   Wt bf16 [3072][1024]
  u16_t* Qb  = (u16_t*)(ws + 14680064);      // 8 MB   Q bf16 [32][2048][64]
  u16_t* Kb  = (u16_t*)(ws + 23068672);      // 8 MB   K bf16
  u16_t* Vb  = (u16_t*)(ws + 31457280);      // 8 MB   V bf16
  u16_t* Vtb = (u16_t*)(ws + 39845888);      // 8 MB   V^T bf16 [32][64][2048]

  hipLaunchKernelGGL(k_cvt_x, dim3(4096), dim3(256), 0, stream, x, xb, 1048576);
  hipLaunchKernelGGL(k_cvt_w, dim3(16, 16, 3), dim3(256), 0, stream, Wq, Wk, Wv, Wt);
  hipLaunchKernelGGL(k_gemm_qkv, dim3(24, 32), dim3(256), 0, stream,
                     xb, Wt, bq, bk, bv, Qb, Kb, Vb);
  hipLaunchKernelGGL(k_trans_v, dim3(32, 32), dim3(256), 0, stream, Vb, Vtb);
  hipLaunchKernelGGL(k_attn, dim3(32, 32), dim3(256), 0, stream, Qb, Kb, Vtb, out);
}

// Round 3
// 172.097 us; speedup vs baseline: 1.2287x; 1.1170x over previous
//
#include <hip/hip_runtime.h>
#include <hip/hip_bf16.h>
#include <stdint.h>

typedef __bf16 bf16x8 __attribute__((ext_vector_type(8)));
typedef __bf16 bf16x4 __attribute__((ext_vector_type(4)));
typedef float  f32x4  __attribute__((ext_vector_type(4)));
typedef unsigned short u16_t;

#define MFMA(a, b, c) __builtin_amdgcn_mfma_f32_16x16x32_bf16((a), (b), (c), 0, 0, 0)

// async global->LDS, 16B per lane; LDS dest is wave-uniform base + lane*16
__device__ __forceinline__ void cp16(const void* g, void* l) {
  __builtin_amdgcn_global_load_lds(
      (const __attribute__((address_space(1))) unsigned int*)g,
      (__attribute__((address_space(3))) unsigned int*)l, 16, 0, 0);
}

__device__ __forceinline__ unsigned pkbf(float a, float b) {  // pack 2 bf16
  __bf16 x = (__bf16)a, y = (__bf16)b;
  return ((unsigned)*(u16_t*)&y << 16) | (unsigned)*(u16_t*)&x;
}

// ---------------- kernel 1: x fp32 -> bf16 ----------------
__global__ __launch_bounds__(256) void k_cvt_x(const float* __restrict__ in,
                                               u16_t* __restrict__ out, int n4) {
  int i = blockIdx.x * 256 + threadIdx.x;
  if (i >= n4) return;
  float4 f = ((const float4*)in)[i];
  bf16x4 o = {(__bf16)f.x, (__bf16)f.y, (__bf16)f.z, (__bf16)f.w};
  *(bf16x4*)&out[(size_t)i * 4] = o;
}

// ------- kernel 2: W[k][n] fp32 -> Wt[mat*1024+n][k] bf16 (transpose) -------
__global__ __launch_bounds__(256) void k_cvt_w(const float* __restrict__ W0,
                                               const float* __restrict__ W1,
                                               const float* __restrict__ W2,
                                               u16_t* __restrict__ Wt) {
  __shared__ u16_t T[64][65];
  const float* W = blockIdx.z == 0 ? W0 : (blockIdx.z == 1 ? W1 : W2);
  int k0 = blockIdx.y * 64, n0 = blockIdx.x * 64;
  int t = threadIdx.x;
#pragma unroll
  for (int i = 0; i < 16; i++) {
    int e = i * 256 + t, r = e >> 6, c = e & 63;
    __bf16 hv = (__bf16)W[(size_t)(k0 + r) * 1024 + n0 + c];
    T[r][c] = *(u16_t*)&hv;
  }
  __syncthreads();
  size_t base = ((size_t)blockIdx.z * 1024 + n0) * 1024 + k0;
#pragma unroll
  for (int i = 0; i < 16; i++) {
    int e = i * 256 + t, r = e >> 6, c = e & 63;
    Wt[base + (size_t)r * 1024 + c] = T[c][r];
  }
}

// ---------------- kernel 3: fused QKV GEMM ----------------
// C[4096,3072] = A[4096,1024] @ Bt[3072,1024]^T, +bias.
// Q: *log2(e)/8 pre-scale, [bh][s][dk]. K: [bh][s][dk]. V: direct-transposed [bh][dk][s].
__global__ __launch_bounds__(256) void k_gemm_qkv(
    const u16_t* __restrict__ A, const u16_t* __restrict__ Bt,
    const float* __restrict__ bq, const float* __restrict__ bk,
    const float* __restrict__ bv,
    u16_t* __restrict__ Qo, u16_t* __restrict__ Ko, u16_t* __restrict__ Vo) {
  __shared__ u16_t As[128 * 32];
  __shared__ u16_t Bs[128 * 32];
  const int tid = threadIdx.x, lane = tid & 63, wv = tid >> 6;
  const int quad = lane >> 4, col = lane & 15;
  const int wm = wv >> 1, wn = wv & 1;
  const int tn = blockIdx.x * 128, tm = blockIdx.y * 128;
  f32x4 acc[4][4] = {};

  const int c0 = wv * 2;
  const int srow = lane >> 2;   // row within 16-row chunk
  const int spc = lane & 3;     // physical 16B k-chunk

  for (int kk = 0; kk < 1024; kk += 32) {
#pragma unroll
    for (int i = 0; i < 2; i++) {
      int c = c0 + i;
      int m = c * 16 + srow;
      int lch = spc ^ ((m >> 1) & 3);  // XOR swizzle
      cp16(A + (size_t)(tm + m) * 1024 + kk + lch * 8, As + c * 512 + lane * 8);
      cp16(Bt + (size_t)(tn + m) * 1024 + kk + lch * 8, Bs + c * 512 + lane * 8);
    }
    __syncthreads();
    bf16x8 af[4], bfv[4];
#pragma unroll
    for (int mt = 0; mt < 4; mt++) {
      int row = wm * 64 + mt * 16 + col;
      af[mt] = *(const bf16x8*)&As[row * 32 + (quad ^ ((row >> 1) & 3)) * 8];
    }
#pragma unroll
    for (int nt = 0; nt < 4; nt++) {
      int row = wn * 64 + nt * 16 + col;
      bfv[nt] = *(const bf16x8*)&Bs[row * 32 + (quad ^ ((row >> 1) & 3)) * 8];
    }
#pragma unroll
    for (int mt = 0; mt < 4; mt++)
#pragma unroll
      for (int nt = 0; nt < 4; nt++)
        acc[mt][nt] = MFMA(af[mt], bfv[nt], acc[mt][nt]);
    __syncthreads();
  }

  const int mat = tn >> 10;  // uniform per block
  const float* bias = mat == 0 ? bq : (mat == 1 ? bk : bv);
  if (mat == 2) {
    // V: write transposed [bh][dk][s]; r-dim = 4 consecutive s -> b64 stores
#pragma unroll
    for (int nt = 0; nt < 4; nt++) {
      int gn = tn + wn * 64 + nt * 16 + col;
      int d = gn & 1023, h = d >> 6, dk = d & 63;
      float bb = bias[d];
#pragma unroll
      for (int mt = 0; mt < 4; mt++) {
        int gm = tm + wm * 64 + mt * 16 + quad * 4;
        int b = gm >> 11, s = gm & 2047;
        bf16x4 pk4;
#pragma unroll
        for (int r = 0; r < 4; r++) pk4[r] = (__bf16)(acc[mt][nt][r] + bb);
        *(bf16x4*)&Vo[((size_t)((b * 16 + h) * 64 + dk)) * 2048 + s] = pk4;
      }
    }
  } else {
    u16_t* O = mat == 0 ? Qo : Ko;
    const float scl = mat == 0 ? 0.18033688011112042f : 1.0f;  // log2(e)/8 folded into Q
#pragma unroll
    for (int nt = 0; nt < 4; nt++) {
      int gn = tn + wn * 64 + nt * 16 + col;
      int d = gn & 1023, h = d >> 6, dk = d & 63;
      float bb = bias[d];
#pragma unroll
      for (int mt = 0; mt < 4; mt++) {
#pragma unroll
        for (int r = 0; r < 4; r++) {
          int gm = tm + wm * 64 + mt * 16 + quad * 4 + r;
          int b = gm >> 11, s = gm & 2047;
          __bf16 hv = (__bf16)((acc[mt][nt][r] + bb) * scl);
          O[((size_t)((b * 16 + h) * 2048 + s)) * 64 + dk] = *(u16_t*)&hv;
        }
      }
    }
  }
}

// ---------------- kernel 4: fused attention (v3) ----------------
// 128 threads = 2 waves; q-tile 64 (all q per wave), keys split across waves.
// S^T = K@Q^T so P-stores are packed b64 into a WAVE-PRIVATE slice (no mid barrier).
// K/V double-buffered, 1 barrier/iter. Partials merged across the 2 waves at end.
__global__ __launch_bounds__(128, 2) void k_attn(const u16_t* __restrict__ Q,
                                                 const u16_t* __restrict__ K,
                                                 const u16_t* __restrict__ Vt,
                                                 float* __restrict__ out) {
  __shared__ u16_t smem[20480];        // 40 KB
  u16_t* Qs  = smem;                   // 8 KB: Q staging, then 2x4KB wave-private P
  u16_t* Ksb = smem + 4096;            // 16 KB dbuf
  u16_t* Vsb = smem + 12288;           // 16 KB dbuf
  const int tid = threadIdx.x, lane = tid & 63, wk = tid >> 6;
  const int quad = lane >> 4, col = lane & 15;
  const int qt = blockIdx.x, bh = blockIdx.y;
  const int b = bh >> 4, h = bh & 15;
  const int r8 = lane >> 3, c8 = lane & 7;

  const u16_t* Qg = Q + ((size_t)bh * 2048 + qt * 64) * 64;
  const u16_t* Kg = K + (size_t)bh * 2048 * 64;
  const u16_t* Vg = Vt + (size_t)bh * 64 * 2048;

  // initial staging: Q + K0 + V0 (XOR-8 swizzled rows)
#pragma unroll
  for (int i = 0; i < 4; i++) {
    int c = wk * 4 + i;
    int row = c * 8 + r8;
    int lch = c8 ^ (row & 7);
    cp16(Qg + (size_t)row * 64 + lch * 8, Qs + c * 512 + lane * 8);
    cp16(Kg + (size_t)row * 64 + lch * 8, Ksb + c * 512 + lane * 8);
    cp16(Vg + (size_t)row * 2048 + lch * 8, Vsb + c * 512 + lane * 8);
  }
  __syncthreads();

  // Q fragments (all 64 q, d=64) -> registers
  bf16x8 qf[4][2];
#pragma unroll
  for (int nt = 0; nt < 4; nt++)
#pragma unroll
    for (int ks = 0; ks < 2; ks++) {
      int row = nt * 16 + col;
      qf[nt][ks] = *(const bf16x8*)&Qs[row * 64 + (((ks * 4 + quad) ^ (row & 7)) * 8)];
    }
  __syncthreads();  // Qs region now free for P

  u16_t* Pw = Qs + wk * 2048;  // wave-private 64q x 32k bf16

  bf16x8 ones;
#pragma unroll
  for (int j = 0; j < 8; j++) ones[j] = (__bf16)1.0f;

  f32x4 ao[4][4] = {};
  f32x4 dn[4] = {};

  for (int kt = 0; kt < 32; kt++) {
    const int cur = kt & 1;
    const u16_t* Kc = Ksb + cur * 4096;
    const u16_t* Vc = Vsb + cur * 4096;
    if (kt + 1 < 32) {
      u16_t* Kn = Ksb + (cur ^ 1) * 4096;
      u16_t* Vn = Vsb + (cur ^ 1) * 4096;
#pragma unroll
      for (int i = 0; i < 4; i++) {
        int c = wk * 4 + i;
        int row = c * 8 + r8;
        int lch = c8 ^ (row & 7);
        cp16(Kg + (size_t)(kt + 1) * 4096 + (size_t)row * 64 + lch * 8,
             Kn + c * 512 + lane * 8);
        cp16(Vg + (size_t)row * 2048 + (kt + 1) * 64 + lch * 8,
             Vn + c * 512 + lane * 8);
      }
    }

    // S^T = K @ Q^T for this wave's 32-key half (A=K-frag, B=Q-frag)
    f32x4 sc[2][4] = {};
#pragma unroll
    for (int ks = 0; ks < 2; ks++) {
      bf16x8 kf[2];
#pragma unroll
      for (int mt = 0; mt < 2; mt++) {
        int row = wk * 32 + mt * 16 + col;
        kf[mt] = *(const bf16x8*)&Kc[row * 64 + (((ks * 4 + quad) ^ (row & 7)) * 8)];
      }
#pragma unroll
      for (int mt = 0; mt < 2; mt++)
#pragma unroll
        for (int nt = 0; nt < 4; nt++)
          sc[mt][nt] = MFMA(kf[mt], qf[nt][ks], sc[mt][nt]);
    }

    // P = exp2(S^T) (Q pre-scaled) -> packed b64 into wave-private slice
#pragma unroll
    for (int mt = 0; mt < 2; mt++)
#pragma unroll
      for (int nt = 0; nt < 4; nt++) {
        int ql = nt * 16 + col;
        unsigned lo = pkbf(__builtin_amdgcn_exp2f(sc[mt][nt][0]),
                           __builtin_amdgcn_exp2f(sc[mt][nt][1]));
        unsigned hi = pkbf(__builtin_amdgcn_exp2f(sc[mt][nt][2]),
                           __builtin_amdgcn_exp2f(sc[mt][nt][3]));
        int kp = (mt * 16 + quad * 4) ^ (((ql >> 1) & 3) << 3);
        *(uint2*)&Pw[ql * 32 + kp] = make_uint2(lo, hi);
      }

    // V fragments
    bf16x8 vf[4];
#pragma unroll
    for (int dt = 0; dt < 4; dt++) {
      int row = dt * 16 + col;
      vf[dt] = *(const bf16x8*)&Vc[row * 64 + (((wk * 4 + quad) ^ (row & 7)) * 8)];
    }

    // O += P @ V ; den += P @ 1  (K=32, wave-private P readback)
#pragma unroll
    for (int nt = 0; nt < 4; nt++) {
      int ql = nt * 16 + col;
      bf16x8 pf = *(const bf16x8*)&Pw[ql * 32 + ((quad * 8) ^ (((ql >> 1) & 3) << 3))];
      dn[nt] = MFMA(pf, ones, dn[nt]);
#pragma unroll
      for (int dt = 0; dt < 4; dt++)
        ao[nt][dt] = MFMA(pf, vf[dt], ao[nt][dt]);
    }
    __syncthreads();  // staging dbuf rotation
  }

  // cross-wave merge: wk=1 dumps partials, wk=0 adds + normalizes + stores
  float* red = (float*)(smem + 4096);  // 32 KB region (K/V dead now)
  if (wk == 1) {
#pragma unroll
    for (int nt = 0; nt < 4; nt++) {
#pragma unroll
      for (int dt = 0; dt < 4; dt++)
#pragma unroll
        for (int r = 0; r < 4; r++)
          red[lane * 81 + (nt * 4 + dt) * 4 + r] = ao[nt][dt][r];
#pragma unroll
      for (int r = 0; r < 4; r++)
        red[lane * 81 + 64 + nt * 4 + r] = dn[nt][r];
    }
  }
  __syncthreads();
  if (wk == 0) {
#pragma unroll
    for (int nt = 0; nt < 4; nt++) {
      float dsum[4];
#pragma unroll
      for (int r = 0; r < 4; r++)
        dsum[r] = dn[nt][r] + red[lane * 81 + 64 + nt * 4 + r] + 1e-8f;
#pragma unroll
      for (int dt = 0; dt < 4; dt++) {
#pragma unroll
        for (int r = 0; r < 4; r++) {
          float v = (ao[nt][dt][r] + red[lane * 81 + (nt * 4 + dt) * 4 + r]) / dsum[r];
          int s = qt * 64 + nt * 16 + quad * 4 + r;
          out[((size_t)b * 2048 + s) * 1024 + h * 64 + dt * 16 + col] = v;
        }
      }
    }
  }
}

// ---------------- launcher ----------------
extern "C" void kernel_launch(void* const* d_in, const int* in_sizes, int n_in,
                              void* d_out, int out_size, void* d_ws, size_t ws_size,
                              hipStream_t stream) {
  const float* x  = (const float*)d_in[0];
  const float* Wq = (const float*)d_in[1];
  const float* bq = (const float*)d_in[2];
  const float* Wk = (const float*)d_in[3];
  const float* bk = (const float*)d_in[4];
  const float* Wv = (const float*)d_in[5];
  const float* bv = (const float*)d_in[6];
  float* out = (float*)d_out;

  char* ws = (char*)d_ws;
  u16_t* xb  = (u16_t*)(ws);                 // 8 MB   x bf16 [4096][1024]
  u16_t* Wt  = (u16_t*)(ws + 8388608);       // 6 MB   Wt bf16 [3072][1024]
  u16_t* Qb  = (u16_t*)(ws + 14680064);      // 8 MB   Q bf16 [bh][s][dk] (pre-scaled)
  u16_t* Kb  = (u16_t*)(ws + 23068672);      // 8 MB   K bf16 [bh][s][dk]
  u16_t* Vtb = (u16_t*)(ws + 31457280);      // 8 MB   V^T bf16 [bh][dk][s]

  hipLaunchKernelGGL(k_cvt_x, dim3(4096), dim3(256), 0, stream, x, xb, 1048576);
  hipLaunchKernelGGL(k_cvt_w, dim3(16, 16, 3), dim3(256), 0, stream, Wq, Wk, Wv, Wt);
  hipLaunchKernelGGL(k_gemm_qkv, dim3(24, 32), dim3(256), 0, stream,
                     xb, Wt, bq, bk, bv, Qb, Kb, Vtb);
  hipLaunchKernelGGL(k_attn, dim3(32, 32), dim3(128), 0, stream, Qb, Kb, Vtb, out);
}